// Round 12
// baseline (48.023 us; speedup 1.0000x reference)
//
#include <hip/hip_runtime.h>

// DynamicMaskHead: per-instance 3-layer 1x1-conv MLP over [rel_xy, feats] at
// 112x200, then AdelaiDet aligned_bilinear 2x upsample to [n,1,224,400].
//
// R12: packed-fp16 dot2 math. 11 rounds showed: instr count +-3x => +-25%
// time; occupancy 16..67% => ~0; barriers/desync => ~0; always ~150 fp32
// FMA/px with thin ILP and any attempt to add waves broke registers. dot2
// (v_dot2_f32_f16: 2 fp16 MACs, fp32 accum) cuts VALU ~1.6x AND packs per-px
// state into ~35 live VGPRs -> launch_bounds(256,8) (cap 64) -> 8 waves/SIMD
// (2x R5). Weights = 76 packed-fp16 SGPR pins (R7-precedent feasible);
// biases via LDS broadcast. fp32 accumulate keeps error ~R5's fp16 regime.

#define IN_C   8
#define CHN    8
#define Hh     112
#define Ww     200
#define HWp    (Hh * Ww)
#define OH     224
#define OW     400
#define TY     16          // output rows per block
#define RL     9           // logit rows needed (TY/2 + 1)
#define NPIX   (RL * Ww)   // 1800
#define NTILES (OH / TY)   // 14
#define NPARAMS 169
#define BLK    256

typedef __fp16 h2v __attribute__((ext_vector_type(2)));

__device__ __forceinline__ uint pkh(float a, float b) {
    h2v p = __builtin_amdgcn_cvt_pkrtz(a, b);
    union { h2v v; uint u; } cv; cv.v = p; return cv.u;
}
__device__ __forceinline__ float fdot2u(uint a, uint b, float c) {
    union { uint u; h2v v; } ua, ub; ua.u = a; ub.u = b;
#if __has_builtin(__builtin_amdgcn_fdot2)
    return __builtin_amdgcn_fdot2(ua.v, ub.v, c, false);
#else
    float d;
    asm("v_dot2_f32_f16 %0, %1, %2, %3" : "=v"(d) : "v"(ua.v), "v"(ub.v), "v"(c));
    return d;
#endif
}

// param layout per instance (169 floats):
// w0 [8][10] @0, w1 [8][8] @80, w2 [8] @144, b0 [8] @152, b1 [8] @160, b2 @168

__global__ __launch_bounds__(BLK, 8)
void dmh_fused_kernel(const float* __restrict__ feats,      // [4][8][112][200]
                      const float* __restrict__ params,     // [n][169]
                      const float* __restrict__ iloc,       // [n][2]
                      const float* __restrict__ soi_tab,    // [5]
                      const int*   __restrict__ im_inds,    // [n]
                      const int*   __restrict__ fpn_levels, // [n]
                      float* __restrict__ out)              // [n][224][400]
{
    __shared__ float bl[20];           // b0[8] @0, b1[8] @8, b2 @16
    __shared__ float lgt[RL][Ww];      // 7.2 KB

    const int bid  = blockIdx.x;
    const int inst = bid / NTILES;
    const int ty   = bid - inst * NTILES;
    const int y0   = ty * TY;
    const int r_lo = (y0 > 0 ? (y0 - 1) : 0) >> 1;   // first logit row of tile
    const int tid  = threadIdx.x;

    const float* __restrict__ wp = params + inst * NPARAMS;
    if (tid < 8)       bl[tid]      = wp[152 + tid];        // b0
    else if (tid < 16) bl[tid]      = wp[160 + (tid - 8)];  // b1
    else if (tid == 16) bl[16]      = wp[168];              // b2

    // ---- pack weights to fp16 pairs, pin in SGPRs (76 pins) ----
    // L0 per o: 5 pairs: (wx,wy),(f0,f1),(f2,f3),(f4,f5),(f6,f7)
    uint w0p[40], w1p[32], w2p[4];
    #pragma unroll
    for (int o = 0; o < CHN; o++) {
        w0p[o * 5 + 0] = pkh(wp[o * 10 + 0], wp[o * 10 + 1]);
        #pragma unroll
        for (int j = 0; j < 4; j++)
            w0p[o * 5 + 1 + j] = pkh(wp[o * 10 + 2 + 2 * j], wp[o * 10 + 3 + 2 * j]);
    }
    #pragma unroll
    for (int o = 0; o < CHN; o++)
        #pragma unroll
        for (int j = 0; j < 4; j++)
            w1p[o * 4 + j] = pkh(wp[80 + o * 8 + 2 * j], wp[80 + o * 8 + 2 * j + 1]);
    #pragma unroll
    for (int j = 0; j < 4; j++)
        w2p[j] = pkh(wp[144 + 2 * j], wp[144 + 2 * j + 1]);

    #pragma unroll
    for (int i = 0; i < 40; i++) {
        w0p[i] = __builtin_amdgcn_readfirstlane(w0p[i]);
        asm volatile("" : "+s"(w0p[i]));
    }
    #pragma unroll
    for (int i = 0; i < 32; i++) {
        w1p[i] = __builtin_amdgcn_readfirstlane(w1p[i]);
        asm volatile("" : "+s"(w1p[i]));
    }
    #pragma unroll
    for (int i = 0; i < 4; i++) {
        w2p[i] = __builtin_amdgcn_readfirstlane(w2p[i]);
        asm volatile("" : "+s"(w2p[i]));
    }

    const float soi    = soi_tab[fpn_levels[inst]];
    const float inv_s  = 1.0f / soi;
    const float ix     = iloc[inst * 2 + 0];
    const float iy     = iloc[inst * 2 + 1];
    const float* __restrict__ fb = feats + (size_t)im_inds[inst] * (IN_C * HWp);

    __syncthreads();   // bl ready

    // ---------- single pass: logits for rows [r_lo, r_lo+RL) ----------
    for (int p = tid; p < NPIX; p += BLK) {
        const int rr = p / Ww;              // 0..8
        const int c  = p - rr * Ww;         // 0..199
        const int r  = r_lo + rr;           // <= 111
        const float* fp = fb + r * Ww + c;

        uint f_pk[4];
        #pragma unroll
        for (int j = 0; j < 4; j++)
            f_pk[j] = pkh(fp[(2 * j) * HWp], fp[(2 * j + 1) * HWp]);

        const float in1 = (iy - (float)(r * 8 + 4)) * inv_s;
        const float in0 = (ix - (float)(c * 8 + 4)) * inv_s;
        const uint  in_pk = pkh(in0, in1);

        float hv[CHN];
        #pragma unroll
        for (int o = 0; o < CHN; o++) {
            float t = bl[o];
            t = fdot2u(in_pk,  w0p[o * 5 + 0], t);
            t = fdot2u(f_pk[0], w0p[o * 5 + 1], t);
            t = fdot2u(f_pk[1], w0p[o * 5 + 2], t);
            t = fdot2u(f_pk[2], w0p[o * 5 + 3], t);
            t = fdot2u(f_pk[3], w0p[o * 5 + 4], t);
            hv[o] = fmaxf(t, 0.0f);
        }
        uint h_pk[4];
        #pragma unroll
        for (int j = 0; j < 4; j++) h_pk[j] = pkh(hv[2 * j], hv[2 * j + 1]);

        float gv[CHN];
        #pragma unroll
        for (int o = 0; o < CHN; o++) {
            float a = bl[8 + o];
            a = fdot2u(h_pk[0], w1p[o * 4 + 0], a);
            a = fdot2u(h_pk[1], w1p[o * 4 + 1], a);
            a = fdot2u(h_pk[2], w1p[o * 4 + 2], a);
            a = fdot2u(h_pk[3], w1p[o * 4 + 3], a);
            gv[o] = fmaxf(a, 0.0f);
        }
        uint g_pk[4];
        #pragma unroll
        for (int j = 0; j < 4; j++) g_pk[j] = pkh(gv[2 * j], gv[2 * j + 1]);

        float r0 = bl[16];
        r0 = fdot2u(g_pk[0], w2p[0], r0);
        r0 = fdot2u(g_pk[1], w2p[1], r0);
        r0 = fdot2u(g_pk[2], w2p[2], r0);
        r0 = fdot2u(g_pk[3], w2p[3], r0);

        lgt[rr][c] = r0;
    }
    __syncthreads();

    // ============ phase C: aligned 2x bilinear, write 16x400 tile ============
    // out[y][x] = interp[max(y-1,0)][max(x-1,0)], weights {1} even / {.5,.5} odd
    float* __restrict__ ob = out + (size_t)inst * (OH * OW);
    const int NQ = (TY * OW) / 4;   // 1600 groups of 4 output px
    for (int q = tid; q < NQ; q += BLK) {
        const int dy = q / (OW / 4);            // 0..15
        const int gx = q - dy * (OW / 4);       // 0..99
        const int x  = gx * 4;
        const int y  = y0 + dy;
        const int i  = (y > 0 ? y - 1 : 0);
        const int rr0 = (i >> 1) - r_lo;
        const int r1g = (i >> 1) + (i & 1);
        const int rr1 = (r1g > Hh - 1 ? Hh - 1 : r1g) - r_lo;
        const float wy1 = (i & 1) ? 0.5f : 0.0f;
        const float wy0 = 1.0f - wy1;

        const int cx  = x >> 1;                 // 0..198 (x even)
        const int cm1 = (cx > 0 ? cx - 1 : 0);
        const float a_m = lgt[rr0][cm1], a_0 = lgt[rr0][cx], a_p = lgt[rr0][cx + 1];
        const float b_m = lgt[rr1][cm1], b_0 = lgt[rr1][cx], b_p = lgt[rr1][cx + 1];
        const float Rm = wy0 * a_m + wy1 * b_m;
        const float R0 = wy0 * a_0 + wy1 * b_0;
        const float Rp = wy0 * a_p + wy1 * b_p;

        float4 o4;
        o4.x = 0.5f * (Rm + R0);   // x+0: odd j (clamped at x=0 where Rm==R0)
        o4.y = R0;                 // x+1: exact col cx
        o4.z = 0.5f * (R0 + Rp);   // x+2: odd j
        o4.w = Rp;                 // x+3: exact col cx+1
        *reinterpret_cast<float4*>(&ob[y * OW + x]) = o4;
    }
}

extern "C" void kernel_launch(void* const* d_in, const int* in_sizes, int n_in,
                              void* d_out, int out_size, void* d_ws, size_t ws_size,
                              hipStream_t stream) {
    const float* mask_feats = (const float*)d_in[0];
    const float* params     = (const float*)d_in[1];
    const float* iloc       = (const float*)d_in[2];
    const float* soi        = (const float*)d_in[3];
    const int*   im_inds    = (const int*)d_in[4];
    const int*   fpn        = (const int*)d_in[5];
    // d_in[6] = mask_feat_stride (=8), baked into the kernel constants.
    float* out = (float*)d_out;

    const int n_inst = in_sizes[4];           // 200
    dim3 grid(n_inst * NTILES);               // 2800 blocks
    dim3 block(BLK);
    hipLaunchKernelGGL(dmh_fused_kernel, grid, block, 0, stream,
                       mask_feats, params, iloc, soi, im_inds, fpn, out);
}

// Round 13
// 43.698 us; speedup vs baseline: 1.0990x; 1.0990x over previous
//
#include <hip/hip_runtime.h>

// DynamicMaskHead: per-instance 3-layer 1x1-conv MLP over [rel_xy, feats] at
// 112x200, then AdelaiDet aligned_bilinear 2x upsample to [n,1,224,400].
//
// R13: NHWC-fp16 feat repack (kernel 1, into d_ws) so the MLP inner loop does
// ONE uint4 load per pixel instead of 8 stride-HWp streams. R12 calibration:
// VALUBusy*dur == static instr count under "any-SIMD-issuing" semantics =>
// per-SIMD issue 15-25%, CU stalled 40% -- load-latency exposure on the
// 8-stream channel gather is the plateau. dot2 math identical to R12
// (absmax 1.95e-3 validated). Weights 76 packed uints + 17 biases as VGPR
// pins at cap 128 (R5-proven configuration class; R3/R10 were 169-f32/SGPR).

#define IN_C   8
#define CHN    8
#define Hh     112
#define Ww     200
#define HWp    (Hh * Ww)
#define OH     224
#define OW     400
#define TY     32          // output rows per block
#define RL     17          // logit rows needed (TY/2 + 1)
#define NPIX   (RL * Ww)   // 3400
#define NTILES (OH / TY)   // 7
#define NPARAMS 169
#define BLK    256

typedef __fp16 h2v __attribute__((ext_vector_type(2)));

__device__ __forceinline__ uint pkh(float a, float b) {
    h2v p = __builtin_amdgcn_cvt_pkrtz(a, b);
    union { h2v v; uint u; } cv; cv.v = p; return cv.u;
}
__device__ __forceinline__ float fdot2u(uint a, uint b, float c) {
    union { uint u; h2v v; } ua, ub; ua.u = a; ub.u = b;
#if __has_builtin(__builtin_amdgcn_fdot2)
    return __builtin_amdgcn_fdot2(ua.v, ub.v, c, false);
#else
    float d;
    asm("v_dot2_f32_f16 %0, %1, %2, %3" : "=v"(d) : "v"(ua.v), "v"(ub.v), "v"(c));
    return d;
#endif
}

// ---------------- kernel 1: feats [4][8][112][200] f32 -> NHWC fp16 pairs ----
__global__ __launch_bounds__(BLK)
void dmh_repack_kernel(const float* __restrict__ feats, uint4* __restrict__ fpk)
{
    const int p = blockIdx.x * BLK + threadIdx.x;   // 0 .. 4*HWp-1
    if (p >= 4 * HWp) return;
    const int img = p / HWp;
    const int px  = p - img * HWp;
    const float* f = feats + (size_t)img * (IN_C * HWp) + px;
    uint4 u;
    u.x = pkh(f[0 * HWp], f[1 * HWp]);
    u.y = pkh(f[2 * HWp], f[3 * HWp]);
    u.z = pkh(f[4 * HWp], f[5 * HWp]);
    u.w = pkh(f[6 * HWp], f[7 * HWp]);
    fpk[p] = u;
}

// param layout per instance (169 floats):
// w0 [8][10] @0, w1 [8][8] @80, w2 [8] @144, b0 [8] @152, b1 [8] @160, b2 @168

__global__ __launch_bounds__(BLK, 4)
void dmh_fused_kernel(const uint4* __restrict__ fpk,        // [4][112*200] packed ch
                      const float* __restrict__ params,     // [n][169]
                      const float* __restrict__ iloc,       // [n][2]
                      const float* __restrict__ soi_tab,    // [5]
                      const int*   __restrict__ im_inds,    // [n]
                      const int*   __restrict__ fpn_levels, // [n]
                      float* __restrict__ out)              // [n][224][400]
{
    __shared__ float lgt[RL][Ww];      // 13.6 KB

    const int bid  = blockIdx.x;
    const int inst = bid / NTILES;
    const int ty   = bid - inst * NTILES;
    const int y0   = ty * TY;
    const int r_lo = (y0 > 0 ? (y0 - 1) : 0) >> 1;   // first logit row of tile
    const int tid  = threadIdx.x;

    const float* __restrict__ wp = params + inst * NPARAMS;

    // ---- pack weights to fp16 pairs; pin in VGPRs (76 + 17 bias = 93 pins) ----
    // L0 per o: (wx,wy),(f0,f1),(f2,f3),(f4,f5),(f6,f7)
    uint w0p[40], w1p[32], w2p[4];
    float b0v[CHN], b1v[CHN], b2v;
    #pragma unroll
    for (int o = 0; o < CHN; o++) {
        w0p[o * 5 + 0] = pkh(wp[o * 10 + 0], wp[o * 10 + 1]);
        #pragma unroll
        for (int j = 0; j < 4; j++)
            w0p[o * 5 + 1 + j] = pkh(wp[o * 10 + 2 + 2 * j], wp[o * 10 + 3 + 2 * j]);
    }
    #pragma unroll
    for (int o = 0; o < CHN; o++)
        #pragma unroll
        for (int j = 0; j < 4; j++)
            w1p[o * 4 + j] = pkh(wp[80 + o * 8 + 2 * j], wp[80 + o * 8 + 2 * j + 1]);
    #pragma unroll
    for (int j = 0; j < 4; j++)
        w2p[j] = pkh(wp[144 + 2 * j], wp[144 + 2 * j + 1]);
    #pragma unroll
    for (int i = 0; i < CHN; i++) b0v[i] = wp[152 + i];
    #pragma unroll
    for (int i = 0; i < CHN; i++) b1v[i] = wp[160 + i];
    b2v = wp[168];

    #pragma unroll
    for (int i = 0; i < 40; i++) asm volatile("" : "+v"(w0p[i]));
    #pragma unroll
    for (int i = 0; i < 32; i++) asm volatile("" : "+v"(w1p[i]));
    #pragma unroll
    for (int i = 0; i < 4; i++)  asm volatile("" : "+v"(w2p[i]));
    #pragma unroll
    for (int i = 0; i < CHN; i++) asm volatile("" : "+v"(b0v[i]));
    #pragma unroll
    for (int i = 0; i < CHN; i++) asm volatile("" : "+v"(b1v[i]));
    asm volatile("" : "+v"(b2v));

    const float soi    = soi_tab[fpn_levels[inst]];
    const float inv_s  = 1.0f / soi;
    const float ix     = iloc[inst * 2 + 0];
    const float iy     = iloc[inst * 2 + 1];
    const uint4* __restrict__ fb = fpk + (size_t)im_inds[inst] * HWp;

    // ---------- single pass: logits for rows [r_lo, r_lo+RL) ----------
    for (int p = tid; p < NPIX; p += BLK) {
        const int rr = p / Ww;              // 0..16
        const int c  = p - rr * Ww;         // 0..199
        const int r  = r_lo + rr;           // <= 111

        const uint4 u = fb[r * Ww + c];     // all 8 channels, one b128 load
        const uint f0 = u.x, f1 = u.y, f2 = u.z, f3 = u.w;

        const float in1 = (iy - (float)(r * 8 + 4)) * inv_s;
        const float in0 = (ix - (float)(c * 8 + 4)) * inv_s;
        const uint  in_pk = pkh(in0, in1);

        float hv[CHN];
        #pragma unroll
        for (int o = 0; o < CHN; o++) {
            float t = b0v[o];
            t = fdot2u(in_pk, w0p[o * 5 + 0], t);
            t = fdot2u(f0,    w0p[o * 5 + 1], t);
            t = fdot2u(f1,    w0p[o * 5 + 2], t);
            t = fdot2u(f2,    w0p[o * 5 + 3], t);
            t = fdot2u(f3,    w0p[o * 5 + 4], t);
            hv[o] = fmaxf(t, 0.0f);
        }
        uint h_pk[4];
        #pragma unroll
        for (int j = 0; j < 4; j++) h_pk[j] = pkh(hv[2 * j], hv[2 * j + 1]);

        float gv[CHN];
        #pragma unroll
        for (int o = 0; o < CHN; o++) {
            float a = b1v[o];
            a = fdot2u(h_pk[0], w1p[o * 4 + 0], a);
            a = fdot2u(h_pk[1], w1p[o * 4 + 1], a);
            a = fdot2u(h_pk[2], w1p[o * 4 + 2], a);
            a = fdot2u(h_pk[3], w1p[o * 4 + 3], a);
            gv[o] = fmaxf(a, 0.0f);
        }
        uint g_pk[4];
        #pragma unroll
        for (int j = 0; j < 4; j++) g_pk[j] = pkh(gv[2 * j], gv[2 * j + 1]);

        float r0 = b2v;
        r0 = fdot2u(g_pk[0], w2p[0], r0);
        r0 = fdot2u(g_pk[1], w2p[1], r0);
        r0 = fdot2u(g_pk[2], w2p[2], r0);
        r0 = fdot2u(g_pk[3], w2p[3], r0);

        lgt[rr][c] = r0;
    }
    __syncthreads();

    // ============ phase C: aligned 2x bilinear, write 32x400 tile ============
    // out[y][x] = interp[max(y-1,0)][max(x-1,0)], weights {1} even / {.5,.5} odd
    float* __restrict__ ob = out + (size_t)inst * (OH * OW);
    const int NQ = (TY * OW) / 4;   // 3200 groups of 4 output px
    for (int q = tid; q < NQ; q += BLK) {
        const int dy = q / (OW / 4);            // 0..31
        const int gx = q - dy * (OW / 4);       // 0..99
        const int x  = gx * 4;
        const int y  = y0 + dy;
        const int i  = (y > 0 ? y - 1 : 0);
        const int rr0 = (i >> 1) - r_lo;
        const int r1g = (i >> 1) + (i & 1);
        const int rr1 = (r1g > Hh - 1 ? Hh - 1 : r1g) - r_lo;
        const float wy1 = (i & 1) ? 0.5f : 0.0f;
        const float wy0 = 1.0f - wy1;

        const int cx  = x >> 1;                 // 0..198 (x even)
        const int cm1 = (cx > 0 ? cx - 1 : 0);
        const float a_m = lgt[rr0][cm1], a_0 = lgt[rr0][cx], a_p = lgt[rr0][cx + 1];
        const float b_m = lgt[rr1][cm1], b_0 = lgt[rr1][cx], b_p = lgt[rr1][cx + 1];
        const float Rm = wy0 * a_m + wy1 * b_m;
        const float R0 = wy0 * a_0 + wy1 * b_0;
        const float Rp = wy0 * a_p + wy1 * b_p;

        float4 o4;
        o4.x = 0.5f * (Rm + R0);   // x+0: odd j (clamped at x=0 where Rm==R0)
        o4.y = R0;                 // x+1: exact col cx
        o4.z = 0.5f * (R0 + Rp);   // x+2: odd j
        o4.w = Rp;                 // x+3: exact col cx+1
        *reinterpret_cast<float4*>(&ob[y * OW + x]) = o4;
    }
}

extern "C" void kernel_launch(void* const* d_in, const int* in_sizes, int n_in,
                              void* d_out, int out_size, void* d_ws, size_t ws_size,
                              hipStream_t stream) {
    const float* mask_feats = (const float*)d_in[0];
    const float* params     = (const float*)d_in[1];
    const float* iloc       = (const float*)d_in[2];
    const float* soi        = (const float*)d_in[3];
    const int*   im_inds    = (const int*)d_in[4];
    const int*   fpn        = (const int*)d_in[5];
    // d_in[6] = mask_feat_stride (=8), baked into the kernel constants.
    float* out = (float*)d_out;
    uint4* fpk = (uint4*)d_ws;                // 4*112*200*16B = 1.434 MB

    const int n_inst = in_sizes[4];           // 200

    dim3 g1((4 * HWp + BLK - 1) / BLK);       // 350 blocks
    hipLaunchKernelGGL(dmh_repack_kernel, g1, dim3(BLK), 0, stream,
                       mask_feats, fpk);

    dim3 g2(n_inst * NTILES);                 // 1400 blocks
    hipLaunchKernelGGL(dmh_fused_kernel, g2, dim3(BLK), 0, stream,
                       fpk, params, iloc, soi, im_inds, fpn, out);
}